// Round 1
// 343.116 us; speedup vs baseline: 1.1195x; 1.1195x over previous
//
#include <hip/hip_runtime.h>
#include <math.h>

// GCN 2-layer forward on MI355X.
// Lessons r2-r6: (a) random 4B global stores => ~130MB writebacks however
// sharded; (b) coarse buckets => 32x re-read in pass 2; (c) LDS-accumulator
// aggregation is latency-serial (1404us); (d) wave-per-node CSR gather agg
// is fast (<=129us, r3/r4). So: one-pass fine bucket partition (391 buckets
// of 256 cols, block-private contiguous runs) -> per-bucket LDS counting
// sort emitting CSR + offsets + dinv with fully coalesced writes -> proven
// CSR gather aggs. log_softmax fused into layer-2 agg.
// r7: aggs were latency-bound (34% HBM, 38% VALU) with only 4 rows in
// flight per wave and 40/64 lanes active in agg2. Rewritten as float4
// row-gathers using all 64 lanes: agg1 = 4 rows/instr unroll 4 (16 rows,
// ~4KB in flight), agg2 = 6 rows/instr unroll 2 (12 rows, ~1.9KB in
// flight), cross-lane reduce via shuffles.

#define NN 100000
#define NE 3200000
#define NBUK 391            // ceil(NN/256); bucket b covers cols [b*256 ...)
#define BCAP 8704           // mean 8184, sd ~90; +5.7 sigma slack
#define EPB 16384           // edges per k_bucket block -> 196 blocks

// ---------------- zero (tail) ----------------

__global__ void k_zero(int* __restrict__ p, int n) {
  int i = blockIdx.x * blockDim.x + threadIdx.x;
  if (i < n) p[i] = 0;
}

// ---------------- one-pass 391-way bucket partition ----------------

__global__ __launch_bounds__(256) void k_bucket(const int* __restrict__ ei,
                                                int* __restrict__ tail,
                                                unsigned* __restrict__ bucket) {
  __shared__ int hist[NBUK], wbase[NBUK], loc[NBUK];
  const int tid = threadIdx.x;
  const int beg = blockIdx.x * EPB;
  const int end = min(beg + EPB, NE);
  const int* col = ei + NE;
  for (int b = tid; b < NBUK; b += 256) { hist[b] = 0; loc[b] = 0; }
  __syncthreads();
  for (int e = beg + tid * 4; e < end; e += 1024) {
    int4 c4 = *(const int4*)(col + e);
    atomicAdd(&hist[c4.x >> 8], 1);
    atomicAdd(&hist[c4.y >> 8], 1);
    atomicAdd(&hist[c4.z >> 8], 1);
    atomicAdd(&hist[c4.w >> 8], 1);
  }
  __syncthreads();
  for (int b = tid; b < NBUK; b += 256)
    wbase[b] = atomicAdd(&tail[b], hist[b]);   // contiguous block-private run
  __syncthreads();
  for (int e = beg + tid * 4; e < end; e += 1024) {
    int4 c4 = *(const int4*)(col + e);         // L2-hot re-read
    int4 r4 = *(const int4*)(ei + e);
    {
      int b = c4.x >> 8;
      unsigned pos = (unsigned)(wbase[b] + atomicAdd(&loc[b], 1));
      if (pos < BCAP) bucket[(size_t)b * BCAP + pos] = ((unsigned)r4.x << 8) | (unsigned)(c4.x & 255);
    }
    {
      int b = c4.y >> 8;
      unsigned pos = (unsigned)(wbase[b] + atomicAdd(&loc[b], 1));
      if (pos < BCAP) bucket[(size_t)b * BCAP + pos] = ((unsigned)r4.y << 8) | (unsigned)(c4.y & 255);
    }
    {
      int b = c4.z >> 8;
      unsigned pos = (unsigned)(wbase[b] + atomicAdd(&loc[b], 1));
      if (pos < BCAP) bucket[(size_t)b * BCAP + pos] = ((unsigned)r4.z << 8) | (unsigned)(c4.z & 255);
    }
    {
      int b = c4.w >> 8;
      unsigned pos = (unsigned)(wbase[b] + atomicAdd(&loc[b], 1));
      if (pos < BCAP) bucket[(size_t)b * BCAP + pos] = ((unsigned)r4.w << 8) | (unsigned)(c4.w & 255);
    }
  }
}

// ---------------- bucket-start prefix sum (391 elems, 1 block) ----------------

__global__ void k_bstart(const int* __restrict__ tail, int* __restrict__ bstart) {
  const int tid = threadIdx.x, lane = tid & 63, wid = tid >> 6;   // 512 thr
  int v = (tid < NBUK) ? min(tail[tid], BCAP) : 0;
  int s = v;
  #pragma unroll
  for (int d = 1; d < 64; d <<= 1) { int t = __shfl_up(s, d, 64); if (lane >= d) s += t; }
  __shared__ int wsum[8];
  if (lane == 63) wsum[wid] = s;
  __syncthreads();
  int wpre = 0;
  for (int w = 0; w < wid; ++w) wpre += wsum[w];
  int excl = wpre + s - v;
  if (tid <= NBUK) bstart[tid] = excl;     // bstart[NBUK] = total
}

// ---------------- per-bucket LDS counting sort -> CSR + offsets + dinv ----------------

__global__ __launch_bounds__(256) void k_sort(const unsigned* __restrict__ bucket,
                                              const int* __restrict__ tail,
                                              const int* __restrict__ bstart,
                                              int* __restrict__ csr_src,
                                              int* __restrict__ offsets,
                                              float* __restrict__ dinv) {
  __shared__ int h[256], base_[256], loc[256];
  __shared__ int sorted[BCAP];              // 34.8 KB
  __shared__ int wsum[4];
  const int b = blockIdx.x;
  const int lo = b << 8;
  const int nc = min(256, NN - lo);
  const int n = min(tail[b], BCAP);
  const int seg0 = bstart[b];
  const unsigned* __restrict__ bk = bucket + (size_t)b * BCAP;
  const int tid = threadIdx.x, lane = tid & 63, wid = tid >> 6;
  h[tid] = 0; loc[tid] = 0;
  __syncthreads();
  int i = tid * 4;
  for (; i + 3 < n; i += 1024) {
    uint4 v = *(const uint4*)(bk + i);
    atomicAdd(&h[v.x & 255u], 1);
    atomicAdd(&h[v.y & 255u], 1);
    atomicAdd(&h[v.z & 255u], 1);
    atomicAdd(&h[v.w & 255u], 1);
  }
  for (; i < n; ++i) atomicAdd(&h[bk[i] & 255u], 1);
  __syncthreads();
  {  // exclusive scan of h[0..255]
    int v = h[tid];
    int s = v;
    #pragma unroll
    for (int d = 1; d < 64; d <<= 1) { int t = __shfl_up(s, d, 64); if (lane >= d) s += t; }
    if (lane == 63) wsum[wid] = s;
    __syncthreads();
    int wpre = 0;
    #pragma unroll
    for (int w = 0; w < 4; ++w) if (w < wid) wpre += wsum[w];
    int excl = wpre + s - v;
    base_[tid] = excl;
    if (tid < nc) {
      dinv[lo + tid] = rsqrtf((float)(v + 1));       // +1 = self-loop
      offsets[lo + tid] = seg0 + excl;
    }
  }
  if (b == 0 && tid == 0) offsets[NN] = bstart[NBUK];
  __syncthreads();
  i = tid * 4;
  for (; i + 3 < n; i += 1024) {
    uint4 v = *(const uint4*)(bk + i);
    { int c = v.x & 255u; sorted[base_[c] + atomicAdd(&loc[c], 1)] = (int)(v.x >> 8); }
    { int c = v.y & 255u; sorted[base_[c] + atomicAdd(&loc[c], 1)] = (int)(v.y >> 8); }
    { int c = v.z & 255u; sorted[base_[c] + atomicAdd(&loc[c], 1)] = (int)(v.z >> 8); }
    { int c = v.w & 255u; sorted[base_[c] + atomicAdd(&loc[c], 1)] = (int)(v.w >> 8); }
  }
  for (; i < n; ++i) {
    unsigned ent = bk[i];
    int c = ent & 255u;
    sorted[base_[c] + atomicAdd(&loc[c], 1)] = (int)(ent >> 8);
  }
  __syncthreads();
  for (int t = tid; t < n; t += 256) csr_src[seg0 + t] = sorted[t];   // coalesced
}

// ---------------- layer 1 GEMM: m1 = dinv * (x @ W1), 128 -> 64 ----------------

__global__ __launch_bounds__(256) void k_gemm1(const float* __restrict__ x,
                                               const float* __restrict__ W1,
                                               const float* __restrict__ dinv,
                                               float* __restrict__ m1) {
  __shared__ float ws[128 * 64];   // 32 KB
  __shared__ float xs[16 * 128];   //  8 KB
  const int tid = threadIdx.x;
  for (int k = tid; k < 128 * 64; k += 256) ws[k] = W1[k];
  const int row0 = blockIdx.x * 16;                    // 6250 blocks
  for (int k = tid; k < 16 * 128; k += 256) xs[k] = x[row0 * 128 + k];
  __syncthreads();
  const int c = tid & 63;
  const int rg = tid >> 6;
  float acc0 = 0.f, acc1 = 0.f, acc2 = 0.f, acc3 = 0.f;
  const float4* xs4 = (const float4*)xs;
  #pragma unroll 8
  for (int k4 = 0; k4 < 32; ++k4) {
    float4 xv0 = xs4[(rg * 4 + 0) * 32 + k4];
    float4 xv1 = xs4[(rg * 4 + 1) * 32 + k4];
    float4 xv2 = xs4[(rg * 4 + 2) * 32 + k4];
    float4 xv3 = xs4[(rg * 4 + 3) * 32 + k4];
    float w0 = ws[(k4 * 4 + 0) * 64 + c];
    float w1 = ws[(k4 * 4 + 1) * 64 + c];
    float w2 = ws[(k4 * 4 + 2) * 64 + c];
    float w3 = ws[(k4 * 4 + 3) * 64 + c];
    acc0 = fmaf(xv0.x, w0, fmaf(xv0.y, w1, fmaf(xv0.z, w2, fmaf(xv0.w, w3, acc0))));
    acc1 = fmaf(xv1.x, w0, fmaf(xv1.y, w1, fmaf(xv1.z, w2, fmaf(xv1.w, w3, acc1))));
    acc2 = fmaf(xv2.x, w0, fmaf(xv2.y, w1, fmaf(xv2.z, w2, fmaf(xv2.w, w3, acc2))));
    acc3 = fmaf(xv3.x, w0, fmaf(xv3.y, w1, fmaf(xv3.z, w2, fmaf(xv3.w, w3, acc3))));
  }
  const int r0 = row0 + rg * 4;
  m1[(r0 + 0) * 64 + c] = acc0 * dinv[r0 + 0];
  m1[(r0 + 1) * 64 + c] = acc1 * dinv[r0 + 1];
  m1[(r0 + 2) * 64 + c] = acc2 * dinv[r0 + 2];
  m1[(r0 + 3) * 64 + c] = acc3 * dinv[r0 + 3];
}

// ---------------- float4 shuffle helpers ----------------

__device__ __forceinline__ float4 shfl_xor4(float4 v, int m) {
  float4 r;
  r.x = __shfl_xor(v.x, m, 64);
  r.y = __shfl_xor(v.y, m, 64);
  r.z = __shfl_xor(v.z, m, 64);
  r.w = __shfl_xor(v.w, m, 64);
  return r;
}

__device__ __forceinline__ float4 shfl4(float4 v, int src) {
  src &= 63;
  float4 r;
  r.x = __shfl(v.x, src, 64);
  r.y = __shfl(v.y, src, 64);
  r.z = __shfl(v.z, src, 64);
  r.w = __shfl(v.w, src, 64);
  return r;
}

// ---------------- layer 1 aggregation (wave-per-node, float4 gather) ----------------
// Lane layout: e = lane>>4 (edge slot 0..3), q = lane&15 (channel quad).
// One vmem instruction gathers 4 full 64-ch rows; unroll 4 => 16 rows
// (~4KB) in flight per wave.

__global__ __launch_bounds__(256) void k_agg1(const float* __restrict__ m1,
                                              const int* __restrict__ offsets,
                                              const int* __restrict__ csr_src,
                                              const float* __restrict__ dinv,
                                              const float* __restrict__ b1,
                                              float* __restrict__ a1) {
  const int node = blockIdx.x * 4 + (threadIdx.x >> 6);
  const int lane = threadIdx.x & 63;
  const int e = lane >> 4;
  const int q = lane & 15;
  const float4* __restrict__ m1v = (const float4*)m1;
  const int beg = offsets[node], end = offsets[node + 1];
  float4 acc = make_float4(0.f, 0.f, 0.f, 0.f);
  int p = beg;
  for (; p + 16 <= end; p += 16) {
    int s0 = csr_src[p + e];
    int s1 = csr_src[p + 4 + e];
    int s2 = csr_src[p + 8 + e];
    int s3 = csr_src[p + 12 + e];
    float4 v0 = m1v[s0 * 16 + q];
    float4 v1 = m1v[s1 * 16 + q];
    float4 v2 = m1v[s2 * 16 + q];
    float4 v3 = m1v[s3 * 16 + q];
    acc.x += (v0.x + v1.x) + (v2.x + v3.x);
    acc.y += (v0.y + v1.y) + (v2.y + v3.y);
    acc.z += (v0.z + v1.z) + (v2.z + v3.z);
    acc.w += (v0.w + v1.w) + (v2.w + v3.w);
  }
  for (; p + 4 <= end; p += 4) {
    int s = csr_src[p + e];
    float4 v = m1v[s * 16 + q];
    acc.x += v.x; acc.y += v.y; acc.z += v.z; acc.w += v.w;
  }
  const int rem = end - p;
  if (rem > 0) {
    int s = csr_src[p + ((e < rem) ? e : 0)];
    float4 v = m1v[s * 16 + q];
    if (e < rem) { acc.x += v.x; acc.y += v.y; acc.z += v.z; acc.w += v.w; }
  }
  // sum the 4 edge slots: xor 16 then 32 -> every lane holds the full sum
  {
    float4 t = shfl_xor4(acc, 16);
    acc.x += t.x; acc.y += t.y; acc.z += t.z; acc.w += t.w;
    t = shfl_xor4(acc, 32);
    acc.x += t.x; acc.y += t.y; acc.z += t.z; acc.w += t.w;
  }
  if (e == 0) {
    float4 self = m1v[node * 16 + q];
    float4 bb = ((const float4*)b1)[q];
    const float d = dinv[node];
    float4 r;
    r.x = (acc.x + self.x) * d + bb.x;
    r.y = (acc.y + self.y) * d + bb.y;
    r.z = (acc.z + self.z) * d + bb.z;
    r.w = (acc.w + self.w) * d + bb.w;
    ((float4*)a1)[node * 16 + q] = r;
  }
}

// ---------------- layer 2 GEMM: m2 = dinv * (a1 @ W2), 64 -> 40 ----------------

__global__ __launch_bounds__(256) void k_gemm2(const float* __restrict__ a1,
                                               const float* __restrict__ W2,
                                               const float* __restrict__ dinv,
                                               float* __restrict__ m2) {
  __shared__ float ws[64 * 40];    // 10 KB
  const int tid = threadIdx.x;
  for (int k = tid; k < 64 * 40; k += 256) ws[k] = W2[k];
  __syncthreads();
  const int idx = blockIdx.x * 256 + tid;                // 15625 blocks
  const int node = idx / 40;
  const int c = idx - node * 40;
  const float* __restrict__ arow = a1 + node * 64;
  float acc = 0.f;
  #pragma unroll
  for (int k = 0; k < 64; ++k) acc = fmaf(arow[k], ws[k * 40 + c], acc);
  m2[idx] = acc * dinv[node];
}

// ---------------- layer 2 aggregation + bias + log_softmax ----------------
// Lane layout: e = lane/10 (edge slot 0..5), q = lane%10 (channel quad);
// lanes 60..63 idle (duplicate lane-0 loads, never read back). One vmem
// instruction gathers 6 full 40-ch rows; unroll 2 => 12 rows (~1.9KB) in
// flight per wave. Reduce 6 slots via 3 shuffles; log_softmax on the
// 10-lane x float4 layout (lanes 10..15 seeded -inf/0 for width-16 xor).

__global__ __launch_bounds__(256) void k_agg2(const float* __restrict__ m2,
                                              const int* __restrict__ offsets,
                                              const int* __restrict__ csr_src,
                                              const float* __restrict__ dinv,
                                              const float* __restrict__ b2,
                                              float* __restrict__ out) {
  const int node = blockIdx.x * 4 + (threadIdx.x >> 6);
  const int lane = threadIdx.x & 63;
  const int e = (lane < 60) ? (lane / 10) : 0;
  const int q = (lane < 60) ? (lane - e * 10) : 0;
  const float4* __restrict__ m2v = (const float4*)m2;
  const int beg = offsets[node], end = offsets[node + 1];
  float4 acc = make_float4(0.f, 0.f, 0.f, 0.f);
  int p = beg;
  for (; p + 12 <= end; p += 12) {
    int sA = csr_src[p + e];
    int sB = csr_src[p + 6 + e];
    float4 vA = m2v[sA * 10 + q];
    float4 vB = m2v[sB * 10 + q];
    acc.x += vA.x + vB.x;
    acc.y += vA.y + vB.y;
    acc.z += vA.z + vB.z;
    acc.w += vA.w + vB.w;
  }
  for (; p + 6 <= end; p += 6) {
    int s = csr_src[p + e];
    float4 v = m2v[s * 10 + q];
    acc.x += v.x; acc.y += v.y; acc.z += v.z; acc.w += v.w;
  }
  const int rem = end - p;
  if (rem > 0) {
    int s = csr_src[p + ((e < rem) ? e : 0)];
    float4 v = m2v[s * 10 + q];
    if (e < rem) { acc.x += v.x; acc.y += v.y; acc.z += v.z; acc.w += v.w; }
  }
  // reduce 6 edge slots down to lanes 0..9:
  // step 1: lanes 0..29 += lanes 30..59  (slots 0..2 += slots 3..5)
  {
    float4 t = shfl4(acc, lane + 30);
    acc.x += t.x; acc.y += t.y; acc.z += t.z; acc.w += t.w;
  }
  // step 2: lanes 0..9 += lanes 10..19 and 20..29
  {
    float4 t1 = shfl4(acc, lane + 10);
    float4 t2 = shfl4(acc, lane + 20);
    acc.x += t1.x + t2.x;
    acc.y += t1.y + t2.y;
    acc.z += t1.z + t2.z;
    acc.w += t1.w + t2.w;
  }
  const bool lead = (lane < 10);
  float4 r = make_float4(0.f, 0.f, 0.f, 0.f);
  {
    float4 self = m2v[node * 10 + q];
    float4 bb = ((const float4*)b2)[q];
    const float d = dinv[node];
    r.x = (acc.x + self.x) * d + bb.x;
    r.y = (acc.y + self.y) * d + bb.y;
    r.z = (acc.z + self.z) * d + bb.z;
    r.w = (acc.w + self.w) * d + bb.w;
  }
  // log_softmax over 40 values spread across lanes 0..9 x 4 components
  float mx = lead ? fmaxf(fmaxf(r.x, r.y), fmaxf(r.z, r.w)) : -INFINITY;
  #pragma unroll
  for (int d = 8; d > 0; d >>= 1) mx = fmaxf(mx, __shfl_xor(mx, d, 16));
  float se = lead ? (__expf(r.x - mx) + __expf(r.y - mx) +
                     __expf(r.z - mx) + __expf(r.w - mx)) : 0.f;
  #pragma unroll
  for (int d = 8; d > 0; d >>= 1) se += __shfl_xor(se, d, 16);
  if (lead) {
    const float lse = mx + logf(se);
    float4 o;
    o.x = r.x - lse; o.y = r.y - lse; o.z = r.z - lse; o.w = r.w - lse;
    ((float4*)out)[node * 10 + q] = o;
  }
}

// ---------------- launch ----------------

extern "C" void kernel_launch(void* const* d_in, const int* in_sizes, int n_in,
                              void* d_out, int out_size, void* d_ws, size_t ws_size,
                              hipStream_t stream) {
  const float* x   = (const float*)d_in[0];
  const int*   ei  = (const int*)d_in[1];   // [2][NE], int32
  const float* W1  = (const float*)d_in[3];
  const float* b1  = (const float*)d_in[4];
  const float* W2  = (const float*)d_in[5];
  const float* b2  = (const float*)d_in[6];
  float*       out = (float*)d_out;

  char* ws = (char*)d_ws;
  int*      tail    = (int*)(ws + 0);                            // NBUK ints
  int*      bstart  = (int*)(ws + (size_t)4 * 1024);             // NBUK+1 ints
  int*      offsets = (int*)(ws + (size_t)8 * 1024);             // (NN+1)*4 = 400KB
  float*    dinv    = (float*)(ws + (size_t)512 * 1024);         // NN*4 = 400KB
  int*      csr_src = (int*)(ws + (size_t)1024 * 1024);          // NE*4 = 12.8MB
  unsigned* bucket  = (unsigned*)(ws + (size_t)14 * 1024 * 1024);// 13.6MB, dead after k_sort
  float*    m1      = (float*)(ws + (size_t)14 * 1024 * 1024);   // 25.6MB (overlays bucket)
  float*    a1      = (float*)(ws + (size_t)40 * 1024 * 1024);   // 25.6MB (ends 65.6MB)
  float*    m2      = m1;   // m1 dead after agg1 (NN*40*4 = 16MB)

  k_zero<<<2, 256, 0, stream>>>(tail, NBUK);
  k_bucket<<<(NE + EPB - 1) / EPB, 256, 0, stream>>>(ei, tail, bucket);
  k_bstart<<<1, 512, 0, stream>>>(tail, bstart);
  k_sort<<<NBUK, 256, 0, stream>>>(bucket, tail, bstart, csr_src, offsets, dinv);
  k_gemm1<<<NN / 16, 256, 0, stream>>>(x, W1, dinv, m1);
  k_agg1<<<NN / 4, 256, 0, stream>>>(m1, offsets, csr_src, dinv, b1, a1);
  k_gemm2<<<(NN * 40) / 256, 256, 0, stream>>>(a1, W2, dinv, m2);
  k_agg2<<<NN / 4, 256, 0, stream>>>(m2, offsets, csr_src, dinv, b2, out);
}

// Round 2
// 337.931 us; speedup vs baseline: 1.1367x; 1.0153x over previous
//
#include <hip/hip_runtime.h>
#include <math.h>

// GCN 2-layer forward on MI355X.
// Lessons r2-r6: (a) random 4B global stores => ~130MB writebacks however
// sharded; (b) coarse buckets => 32x re-read in pass 2; (c) LDS-accumulator
// aggregation is latency-serial (1404us); (d) wave-per-node CSR gather agg
// is fast (<=129us, r3/r4). So: one-pass fine bucket partition (391 buckets
// of 256 cols, block-private contiguous runs) -> per-bucket LDS counting
// sort emitting CSR + offsets + dinv with fully coalesced writes -> proven
// CSR gather aggs. log_softmax fused into layer-2 agg.
// r7: aggs rewritten as float4 row-gathers using all 64 lanes (agg1: 4
// rows/instr, agg2: 6 rows/instr). agg2 124->~95, agg1 ->105us.
// r8: aggs still latency-bound (agg1: 47% HBM, 19% VALU) because the
// 16-edge main loop + 4-edge tail expose ~4-6 serial idx->gather chains
// per node (deg~Poisson(32)). Replaced with single-shot masked wide
// chunks: agg1 = 32 edges/chunk (8 slots), agg2 = 48 edges/chunk (8
// slots); invalid slots clamp index to beg and multiply by 0.0 in the
// FMA. One serial chain per ~chunk, no scalar tail.

#define NN 100000
#define NE 3200000
#define NBUK 391            // ceil(NN/256); bucket b covers cols [b*256 ...)
#define BCAP 8704           // mean 8184, sd ~90; +5.7 sigma slack
#define EPB 16384           // edges per k_bucket block -> 196 blocks

// ---------------- zero (tail) ----------------

__global__ void k_zero(int* __restrict__ p, int n) {
  int i = blockIdx.x * blockDim.x + threadIdx.x;
  if (i < n) p[i] = 0;
}

// ---------------- one-pass 391-way bucket partition ----------------

__global__ __launch_bounds__(256) void k_bucket(const int* __restrict__ ei,
                                                int* __restrict__ tail,
                                                unsigned* __restrict__ bucket) {
  __shared__ int hist[NBUK], wbase[NBUK], loc[NBUK];
  const int tid = threadIdx.x;
  const int beg = blockIdx.x * EPB;
  const int end = min(beg + EPB, NE);
  const int* col = ei + NE;
  for (int b = tid; b < NBUK; b += 256) { hist[b] = 0; loc[b] = 0; }
  __syncthreads();
  for (int e = beg + tid * 4; e < end; e += 1024) {
    int4 c4 = *(const int4*)(col + e);
    atomicAdd(&hist[c4.x >> 8], 1);
    atomicAdd(&hist[c4.y >> 8], 1);
    atomicAdd(&hist[c4.z >> 8], 1);
    atomicAdd(&hist[c4.w >> 8], 1);
  }
  __syncthreads();
  for (int b = tid; b < NBUK; b += 256)
    wbase[b] = atomicAdd(&tail[b], hist[b]);   // contiguous block-private run
  __syncthreads();
  for (int e = beg + tid * 4; e < end; e += 1024) {
    int4 c4 = *(const int4*)(col + e);         // L2-hot re-read
    int4 r4 = *(const int4*)(ei + e);
    {
      int b = c4.x >> 8;
      unsigned pos = (unsigned)(wbase[b] + atomicAdd(&loc[b], 1));
      if (pos < BCAP) bucket[(size_t)b * BCAP + pos] = ((unsigned)r4.x << 8) | (unsigned)(c4.x & 255);
    }
    {
      int b = c4.y >> 8;
      unsigned pos = (unsigned)(wbase[b] + atomicAdd(&loc[b], 1));
      if (pos < BCAP) bucket[(size_t)b * BCAP + pos] = ((unsigned)r4.y << 8) | (unsigned)(c4.y & 255);
    }
    {
      int b = c4.z >> 8;
      unsigned pos = (unsigned)(wbase[b] + atomicAdd(&loc[b], 1));
      if (pos < BCAP) bucket[(size_t)b * BCAP + pos] = ((unsigned)r4.z << 8) | (unsigned)(c4.z & 255);
    }
    {
      int b = c4.w >> 8;
      unsigned pos = (unsigned)(wbase[b] + atomicAdd(&loc[b], 1));
      if (pos < BCAP) bucket[(size_t)b * BCAP + pos] = ((unsigned)r4.w << 8) | (unsigned)(c4.w & 255);
    }
  }
}

// ---------------- bucket-start prefix sum (391 elems, 1 block) ----------------

__global__ void k_bstart(const int* __restrict__ tail, int* __restrict__ bstart) {
  const int tid = threadIdx.x, lane = tid & 63, wid = tid >> 6;   // 512 thr
  int v = (tid < NBUK) ? min(tail[tid], BCAP) : 0;
  int s = v;
  #pragma unroll
  for (int d = 1; d < 64; d <<= 1) { int t = __shfl_up(s, d, 64); if (lane >= d) s += t; }
  __shared__ int wsum[8];
  if (lane == 63) wsum[wid] = s;
  __syncthreads();
  int wpre = 0;
  for (int w = 0; w < wid; ++w) wpre += wsum[w];
  int excl = wpre + s - v;
  if (tid <= NBUK) bstart[tid] = excl;     // bstart[NBUK] = total
}

// ---------------- per-bucket LDS counting sort -> CSR + offsets + dinv ----------------

__global__ __launch_bounds__(256) void k_sort(const unsigned* __restrict__ bucket,
                                              const int* __restrict__ tail,
                                              const int* __restrict__ bstart,
                                              int* __restrict__ csr_src,
                                              int* __restrict__ offsets,
                                              float* __restrict__ dinv) {
  __shared__ int h[256], base_[256], loc[256];
  __shared__ int sorted[BCAP];              // 34.8 KB
  __shared__ int wsum[4];
  const int b = blockIdx.x;
  const int lo = b << 8;
  const int nc = min(256, NN - lo);
  const int n = min(tail[b], BCAP);
  const int seg0 = bstart[b];
  const unsigned* __restrict__ bk = bucket + (size_t)b * BCAP;
  const int tid = threadIdx.x, lane = tid & 63, wid = tid >> 6;
  h[tid] = 0; loc[tid] = 0;
  __syncthreads();
  int i = tid * 4;
  for (; i + 3 < n; i += 1024) {
    uint4 v = *(const uint4*)(bk + i);
    atomicAdd(&h[v.x & 255u], 1);
    atomicAdd(&h[v.y & 255u], 1);
    atomicAdd(&h[v.z & 255u], 1);
    atomicAdd(&h[v.w & 255u], 1);
  }
  for (; i < n; ++i) atomicAdd(&h[bk[i] & 255u], 1);
  __syncthreads();
  {  // exclusive scan of h[0..255]
    int v = h[tid];
    int s = v;
    #pragma unroll
    for (int d = 1; d < 64; d <<= 1) { int t = __shfl_up(s, d, 64); if (lane >= d) s += t; }
    if (lane == 63) wsum[wid] = s;
    __syncthreads();
    int wpre = 0;
    #pragma unroll
    for (int w = 0; w < 4; ++w) if (w < wid) wpre += wsum[w];
    int excl = wpre + s - v;
    base_[tid] = excl;
    if (tid < nc) {
      dinv[lo + tid] = rsqrtf((float)(v + 1));       // +1 = self-loop
      offsets[lo + tid] = seg0 + excl;
    }
  }
  if (b == 0 && tid == 0) offsets[NN] = bstart[NBUK];
  __syncthreads();
  i = tid * 4;
  for (; i + 3 < n; i += 1024) {
    uint4 v = *(const uint4*)(bk + i);
    { int c = v.x & 255u; sorted[base_[c] + atomicAdd(&loc[c], 1)] = (int)(v.x >> 8); }
    { int c = v.y & 255u; sorted[base_[c] + atomicAdd(&loc[c], 1)] = (int)(v.y >> 8); }
    { int c = v.z & 255u; sorted[base_[c] + atomicAdd(&loc[c], 1)] = (int)(v.z >> 8); }
    { int c = v.w & 255u; sorted[base_[c] + atomicAdd(&loc[c], 1)] = (int)(v.w >> 8); }
  }
  for (; i < n; ++i) {
    unsigned ent = bk[i];
    int c = ent & 255u;
    sorted[base_[c] + atomicAdd(&loc[c], 1)] = (int)(ent >> 8);
  }
  __syncthreads();
  for (int t = tid; t < n; t += 256) csr_src[seg0 + t] = sorted[t];   // coalesced
}

// ---------------- layer 1 GEMM: m1 = dinv * (x @ W1), 128 -> 64 ----------------

__global__ __launch_bounds__(256) void k_gemm1(const float* __restrict__ x,
                                               const float* __restrict__ W1,
                                               const float* __restrict__ dinv,
                                               float* __restrict__ m1) {
  __shared__ float ws[128 * 64];   // 32 KB
  __shared__ float xs[16 * 128];   //  8 KB
  const int tid = threadIdx.x;
  for (int k = tid; k < 128 * 64; k += 256) ws[k] = W1[k];
  const int row0 = blockIdx.x * 16;                    // 6250 blocks
  for (int k = tid; k < 16 * 128; k += 256) xs[k] = x[row0 * 128 + k];
  __syncthreads();
  const int c = tid & 63;
  const int rg = tid >> 6;
  float acc0 = 0.f, acc1 = 0.f, acc2 = 0.f, acc3 = 0.f;
  const float4* xs4 = (const float4*)xs;
  #pragma unroll 8
  for (int k4 = 0; k4 < 32; ++k4) {
    float4 xv0 = xs4[(rg * 4 + 0) * 32 + k4];
    float4 xv1 = xs4[(rg * 4 + 1) * 32 + k4];
    float4 xv2 = xs4[(rg * 4 + 2) * 32 + k4];
    float4 xv3 = xs4[(rg * 4 + 3) * 32 + k4];
    float w0 = ws[(k4 * 4 + 0) * 64 + c];
    float w1 = ws[(k4 * 4 + 1) * 64 + c];
    float w2 = ws[(k4 * 4 + 2) * 64 + c];
    float w3 = ws[(k4 * 4 + 3) * 64 + c];
    acc0 = fmaf(xv0.x, w0, fmaf(xv0.y, w1, fmaf(xv0.z, w2, fmaf(xv0.w, w3, acc0))));
    acc1 = fmaf(xv1.x, w0, fmaf(xv1.y, w1, fmaf(xv1.z, w2, fmaf(xv1.w, w3, acc1))));
    acc2 = fmaf(xv2.x, w0, fmaf(xv2.y, w1, fmaf(xv2.z, w2, fmaf(xv2.w, w3, acc2))));
    acc3 = fmaf(xv3.x, w0, fmaf(xv3.y, w1, fmaf(xv3.z, w2, fmaf(xv3.w, w3, acc3))));
  }
  const int r0 = row0 + rg * 4;
  m1[(r0 + 0) * 64 + c] = acc0 * dinv[r0 + 0];
  m1[(r0 + 1) * 64 + c] = acc1 * dinv[r0 + 1];
  m1[(r0 + 2) * 64 + c] = acc2 * dinv[r0 + 2];
  m1[(r0 + 3) * 64 + c] = acc3 * dinv[r0 + 3];
}

// ---------------- float4 shuffle helpers ----------------

__device__ __forceinline__ float4 shfl_xor4(float4 v, int m) {
  float4 r;
  r.x = __shfl_xor(v.x, m, 64);
  r.y = __shfl_xor(v.y, m, 64);
  r.z = __shfl_xor(v.z, m, 64);
  r.w = __shfl_xor(v.w, m, 64);
  return r;
}

__device__ __forceinline__ float4 shfl4(float4 v, int src) {
  src &= 63;
  float4 r;
  r.x = __shfl(v.x, src, 64);
  r.y = __shfl(v.y, src, 64);
  r.z = __shfl(v.z, src, 64);
  r.w = __shfl(v.w, src, 64);
  return r;
}

// ---------------- layer 1 aggregation (wave-per-node, masked wide gather) ----
// Lane layout: e = lane>>4 (edge slot), q = lane&15 (channel quad). One
// masked chunk = 32 edges (8 slots x 4 rows/instr): all 8 index loads and
// all 8 row gathers issue together -> one idx->gather serial chain per
// chunk, ~1.5 chunks per node (deg~Poisson(32)). Invalid slots clamp the
// index to beg (in-bounds broadcast, L1-hot) and contribute via fma x0.0.

__global__ __launch_bounds__(256) void k_agg1(const float* __restrict__ m1,
                                              const int* __restrict__ offsets,
                                              const int* __restrict__ csr_src,
                                              const float* __restrict__ dinv,
                                              const float* __restrict__ b1,
                                              float* __restrict__ a1) {
  const int node = blockIdx.x * 4 + (threadIdx.x >> 6);
  const int lane = threadIdx.x & 63;
  const int e = lane >> 4;
  const int q = lane & 15;
  const float4* __restrict__ m1v = (const float4*)m1;
  const int beg = offsets[node], end = offsets[node + 1];
  float4 accA = make_float4(0.f, 0.f, 0.f, 0.f);
  float4 accB = make_float4(0.f, 0.f, 0.f, 0.f);
  for (int p = beg; p < end; p += 32) {
    const int i0 = p + e,      i1 = p + 4 + e,  i2 = p + 8 + e,  i3 = p + 12 + e;
    const int i4 = p + 16 + e, i5 = p + 20 + e, i6 = p + 24 + e, i7 = p + 28 + e;
    const int s0 = csr_src[i0 < end ? i0 : beg];
    const int s1 = csr_src[i1 < end ? i1 : beg];
    const int s2 = csr_src[i2 < end ? i2 : beg];
    const int s3 = csr_src[i3 < end ? i3 : beg];
    const int s4 = csr_src[i4 < end ? i4 : beg];
    const int s5 = csr_src[i5 < end ? i5 : beg];
    const int s6 = csr_src[i6 < end ? i6 : beg];
    const int s7 = csr_src[i7 < end ? i7 : beg];
    const float f0 = (i0 < end) ? 1.f : 0.f;
    const float f1 = (i1 < end) ? 1.f : 0.f;
    const float f2 = (i2 < end) ? 1.f : 0.f;
    const float f3 = (i3 < end) ? 1.f : 0.f;
    const float f4 = (i4 < end) ? 1.f : 0.f;
    const float f5 = (i5 < end) ? 1.f : 0.f;
    const float f6 = (i6 < end) ? 1.f : 0.f;
    const float f7 = (i7 < end) ? 1.f : 0.f;
    float4 v0 = m1v[s0 * 16 + q];
    float4 v1 = m1v[s1 * 16 + q];
    float4 v2 = m1v[s2 * 16 + q];
    float4 v3 = m1v[s3 * 16 + q];
    float4 v4 = m1v[s4 * 16 + q];
    float4 v5 = m1v[s5 * 16 + q];
    float4 v6 = m1v[s6 * 16 + q];
    float4 v7 = m1v[s7 * 16 + q];
    accA.x = fmaf(v0.x, f0, fmaf(v1.x, f1, fmaf(v2.x, f2, fmaf(v3.x, f3, accA.x))));
    accA.y = fmaf(v0.y, f0, fmaf(v1.y, f1, fmaf(v2.y, f2, fmaf(v3.y, f3, accA.y))));
    accA.z = fmaf(v0.z, f0, fmaf(v1.z, f1, fmaf(v2.z, f2, fmaf(v3.z, f3, accA.z))));
    accA.w = fmaf(v0.w, f0, fmaf(v1.w, f1, fmaf(v2.w, f2, fmaf(v3.w, f3, accA.w))));
    accB.x = fmaf(v4.x, f4, fmaf(v5.x, f5, fmaf(v6.x, f6, fmaf(v7.x, f7, accB.x))));
    accB.y = fmaf(v4.y, f4, fmaf(v5.y, f5, fmaf(v6.y, f6, fmaf(v7.y, f7, accB.y))));
    accB.z = fmaf(v4.z, f4, fmaf(v5.z, f5, fmaf(v6.z, f6, fmaf(v7.z, f7, accB.z))));
    accB.w = fmaf(v4.w, f4, fmaf(v5.w, f5, fmaf(v6.w, f6, fmaf(v7.w, f7, accB.w))));
  }
  float4 acc;
  acc.x = accA.x + accB.x;
  acc.y = accA.y + accB.y;
  acc.z = accA.z + accB.z;
  acc.w = accA.w + accB.w;
  // sum the 4 edge slots: xor 16 then 32 -> every lane holds the full sum
  {
    float4 t = shfl_xor4(acc, 16);
    acc.x += t.x; acc.y += t.y; acc.z += t.z; acc.w += t.w;
    t = shfl_xor4(acc, 32);
    acc.x += t.x; acc.y += t.y; acc.z += t.z; acc.w += t.w;
  }
  if (e == 0) {
    float4 self = m1v[node * 16 + q];
    float4 bb = ((const float4*)b1)[q];
    const float d = dinv[node];
    float4 r;
    r.x = (acc.x + self.x) * d + bb.x;
    r.y = (acc.y + self.y) * d + bb.y;
    r.z = (acc.z + self.z) * d + bb.z;
    r.w = (acc.w + self.w) * d + bb.w;
    ((float4*)a1)[node * 16 + q] = r;
  }
}

// ---------------- layer 2 GEMM: m2 = dinv * (a1 @ W2), 64 -> 40 ----------------

__global__ __launch_bounds__(256) void k_gemm2(const float* __restrict__ a1,
                                               const float* __restrict__ W2,
                                               const float* __restrict__ dinv,
                                               float* __restrict__ m2) {
  __shared__ float ws[64 * 40];    // 10 KB
  const int tid = threadIdx.x;
  for (int k = tid; k < 64 * 40; k += 256) ws[k] = W2[k];
  __syncthreads();
  const int idx = blockIdx.x * 256 + tid;                // 15625 blocks
  const int node = idx / 40;
  const int c = idx - node * 40;
  const float* __restrict__ arow = a1 + node * 64;
  float acc = 0.f;
  #pragma unroll
  for (int k = 0; k < 64; ++k) acc = fmaf(arow[k], ws[k * 40 + c], acc);
  m2[idx] = acc * dinv[node];
}

// ---------------- layer 2 aggregation + bias + log_softmax ----------------
// Lane layout: e = lane/10 (edge slot 0..5), q = lane%10 (channel quad);
// lanes 60..63 duplicate slot0/q0, never read back. One masked chunk =
// 48 edges (8 slots x 6 rows/instr) -> ~1.03 chunks per node. Reduce 6
// slots via 3 shuffles; log_softmax on the 10-lane x float4 layout.

__global__ __launch_bounds__(256) void k_agg2(const float* __restrict__ m2,
                                              const int* __restrict__ offsets,
                                              const int* __restrict__ csr_src,
                                              const float* __restrict__ dinv,
                                              const float* __restrict__ b2,
                                              float* __restrict__ out) {
  const int node = blockIdx.x * 4 + (threadIdx.x >> 6);
  const int lane = threadIdx.x & 63;
  const int e = (lane < 60) ? (lane / 10) : 0;
  const int q = (lane < 60) ? (lane - e * 10) : 0;
  const float4* __restrict__ m2v = (const float4*)m2;
  const int beg = offsets[node], end = offsets[node + 1];
  float4 accA = make_float4(0.f, 0.f, 0.f, 0.f);
  float4 accB = make_float4(0.f, 0.f, 0.f, 0.f);
  for (int p = beg; p < end; p += 48) {
    const int i0 = p + e,      i1 = p + 6 + e,  i2 = p + 12 + e, i3 = p + 18 + e;
    const int i4 = p + 24 + e, i5 = p + 30 + e, i6 = p + 36 + e, i7 = p + 42 + e;
    const int s0 = csr_src[i0 < end ? i0 : beg];
    const int s1 = csr_src[i1 < end ? i1 : beg];
    const int s2 = csr_src[i2 < end ? i2 : beg];
    const int s3 = csr_src[i3 < end ? i3 : beg];
    const int s4 = csr_src[i4 < end ? i4 : beg];
    const int s5 = csr_src[i5 < end ? i5 : beg];
    const int s6 = csr_src[i6 < end ? i6 : beg];
    const int s7 = csr_src[i7 < end ? i7 : beg];
    const float f0 = (i0 < end) ? 1.f : 0.f;
    const float f1 = (i1 < end) ? 1.f : 0.f;
    const float f2 = (i2 < end) ? 1.f : 0.f;
    const float f3 = (i3 < end) ? 1.f : 0.f;
    const float f4 = (i4 < end) ? 1.f : 0.f;
    const float f5 = (i5 < end) ? 1.f : 0.f;
    const float f6 = (i6 < end) ? 1.f : 0.f;
    const float f7 = (i7 < end) ? 1.f : 0.f;
    float4 v0 = m2v[s0 * 10 + q];
    float4 v1 = m2v[s1 * 10 + q];
    float4 v2 = m2v[s2 * 10 + q];
    float4 v3 = m2v[s3 * 10 + q];
    float4 v4 = m2v[s4 * 10 + q];
    float4 v5 = m2v[s5 * 10 + q];
    float4 v6 = m2v[s6 * 10 + q];
    float4 v7 = m2v[s7 * 10 + q];
    accA.x = fmaf(v0.x, f0, fmaf(v1.x, f1, fmaf(v2.x, f2, fmaf(v3.x, f3, accA.x))));
    accA.y = fmaf(v0.y, f0, fmaf(v1.y, f1, fmaf(v2.y, f2, fmaf(v3.y, f3, accA.y))));
    accA.z = fmaf(v0.z, f0, fmaf(v1.z, f1, fmaf(v2.z, f2, fmaf(v3.z, f3, accA.z))));
    accA.w = fmaf(v0.w, f0, fmaf(v1.w, f1, fmaf(v2.w, f2, fmaf(v3.w, f3, accA.w))));
    accB.x = fmaf(v4.x, f4, fmaf(v5.x, f5, fmaf(v6.x, f6, fmaf(v7.x, f7, accB.x))));
    accB.y = fmaf(v4.y, f4, fmaf(v5.y, f5, fmaf(v6.y, f6, fmaf(v7.y, f7, accB.y))));
    accB.z = fmaf(v4.z, f4, fmaf(v5.z, f5, fmaf(v6.z, f6, fmaf(v7.z, f7, accB.z))));
    accB.w = fmaf(v4.w, f4, fmaf(v5.w, f5, fmaf(v6.w, f6, fmaf(v7.w, f7, accB.w))));
  }
  float4 acc;
  acc.x = accA.x + accB.x;
  acc.y = accA.y + accB.y;
  acc.z = accA.z + accB.z;
  acc.w = accA.w + accB.w;
  // reduce 6 edge slots down to lanes 0..9:
  // step 1: lanes 0..29 += lanes 30..59  (slots 0..2 += slots 3..5)
  {
    float4 t = shfl4(acc, lane + 30);
    acc.x += t.x; acc.y += t.y; acc.z += t.z; acc.w += t.w;
  }
  // step 2: lanes 0..9 += lanes 10..19 and 20..29
  {
    float4 t1 = shfl4(acc, lane + 10);
    float4 t2 = shfl4(acc, lane + 20);
    acc.x += t1.x + t2.x;
    acc.y += t1.y + t2.y;
    acc.z += t1.z + t2.z;
    acc.w += t1.w + t2.w;
  }
  const bool lead = (lane < 10);
  float4 r = make_float4(0.f, 0.f, 0.f, 0.f);
  {
    float4 self = m2v[node * 10 + q];
    float4 bb = ((const float4*)b2)[q];
    const float d = dinv[node];
    r.x = (acc.x + self.x) * d + bb.x;
    r.y = (acc.y + self.y) * d + bb.y;
    r.z = (acc.z + self.z) * d + bb.z;
    r.w = (acc.w + self.w) * d + bb.w;
  }
  // log_softmax over 40 values spread across lanes 0..9 x 4 components
  float mx = lead ? fmaxf(fmaxf(r.x, r.y), fmaxf(r.z, r.w)) : -INFINITY;
  #pragma unroll
  for (int d = 8; d > 0; d >>= 1) mx = fmaxf(mx, __shfl_xor(mx, d, 16));
  float se = lead ? (__expf(r.x - mx) + __expf(r.y - mx) +
                     __expf(r.z - mx) + __expf(r.w - mx)) : 0.f;
  #pragma unroll
  for (int d = 8; d > 0; d >>= 1) se += __shfl_xor(se, d, 16);
  if (lead) {
    const float lse = mx + logf(se);
    float4 o;
    o.x = r.x - lse; o.y = r.y - lse; o.z = r.z - lse; o.w = r.w - lse;
    ((float4*)out)[node * 10 + q] = o;
  }
}

// ---------------- launch ----------------

extern "C" void kernel_launch(void* const* d_in, const int* in_sizes, int n_in,
                              void* d_out, int out_size, void* d_ws, size_t ws_size,
                              hipStream_t stream) {
  const float* x   = (const float*)d_in[0];
  const int*   ei  = (const int*)d_in[1];   // [2][NE], int32
  const float* W1  = (const float*)d_in[3];
  const float* b1  = (const float*)d_in[4];
  const float* W2  = (const float*)d_in[5];
  const float* b2  = (const float*)d_in[6];
  float*       out = (float*)d_out;

  char* ws = (char*)d_ws;
  int*      tail    = (int*)(ws + 0);                            // NBUK ints
  int*      bstart  = (int*)(ws + (size_t)4 * 1024);             // NBUK+1 ints
  int*      offsets = (int*)(ws + (size_t)8 * 1024);             // (NN+1)*4 = 400KB
  float*    dinv    = (float*)(ws + (size_t)512 * 1024);         // NN*4 = 400KB
  int*      csr_src = (int*)(ws + (size_t)1024 * 1024);          // NE*4 = 12.8MB
  unsigned* bucket  = (unsigned*)(ws + (size_t)14 * 1024 * 1024);// 13.6MB, dead after k_sort
  float*    m1      = (float*)(ws + (size_t)14 * 1024 * 1024);   // 25.6MB (overlays bucket)
  float*    a1      = (float*)(ws + (size_t)40 * 1024 * 1024);   // 25.6MB (ends 65.6MB)
  float*    m2      = m1;   // m1 dead after agg1 (NN*40*4 = 16MB)

  k_zero<<<2, 256, 0, stream>>>(tail, NBUK);
  k_bucket<<<(NE + EPB - 1) / EPB, 256, 0, stream>>>(ei, tail, bucket);
  k_bstart<<<1, 512, 0, stream>>>(tail, bstart);
  k_sort<<<NBUK, 256, 0, stream>>>(bucket, tail, bstart, csr_src, offsets, dinv);
  k_gemm1<<<NN / 16, 256, 0, stream>>>(x, W1, dinv, m1);
  k_agg1<<<NN / 4, 256, 0, stream>>>(m1, offsets, csr_src, dinv, b1, a1);
  k_gemm2<<<(NN * 40) / 256, 256, 0, stream>>>(a1, W2, dinv, m2);
  k_agg2<<<NN / 4, 256, 0, stream>>>(m2, offsets, csr_src, dinv, b2, out);
}

// Round 3
// 236.073 us; speedup vs baseline: 1.6271x; 1.4315x over previous
//
#include <hip/hip_runtime.h>
#include <math.h>

// GCN 2-layer forward on MI355X.
// Lessons r2-r6: (a) random 4B global stores => ~130MB writebacks however
// sharded; (b) coarse buckets => 32x re-read in pass 2; (c) LDS-accumulator
// aggregation is latency-serial (1404us); (d) wave-per-node CSR gather agg
// is fast (<=129us, r3/r4). One-pass fine bucket partition -> per-bucket
// LDS counting sort -> CSR gather aggs; log_softmax fused into agg2.
// r7: float4 row-gathers, all 64 lanes. r8: masked 32/48-edge chunks, one
// idx->gather chain per chunk. Result: agg1 pinned at 104us / 3.8 TB/s
// L2-miss rate with FETCH=362MB for BOTH r7 and r8 => the random-row
// gather path is byte/request ceilinged; more MLP does nothing.
// r9: halve gathered bytes: m1/m2 stored as bf16 (RNE). Rows 128B/80B;
// agg1 = 8 rows per dwordx4 instr (8 slots x 8 lanes), agg2 = 12 rows
// per instr (12 slots x 5 lanes). Unpack = shift/and folded into FMA.
// Accumulate fp32; a1/out stay fp32.

#define NN 100000
#define NE 3200000
#define NBUK 391            // ceil(NN/256); bucket b covers cols [b*256 ...)
#define BCAP 8704           // mean 8184, sd ~90; +5.7 sigma slack
#define EPB 16384           // edges per k_bucket block -> 196 blocks

// ---------------- zero (tail) ----------------

__global__ void k_zero(int* __restrict__ p, int n) {
  int i = blockIdx.x * blockDim.x + threadIdx.x;
  if (i < n) p[i] = 0;
}

// ---------------- bf16 helpers ----------------

__device__ __forceinline__ unsigned bf16rne(float x) {
  unsigned u = __float_as_uint(x);
  return (u + 0x7fffu + ((u >> 16) & 1u)) >> 16;
}
__device__ __forceinline__ unsigned pack2(float lo, float hi) {
  return bf16rne(lo) | (bf16rne(hi) << 16);
}

// ---------------- one-pass 391-way bucket partition ----------------

__global__ __launch_bounds__(256) void k_bucket(const int* __restrict__ ei,
                                                int* __restrict__ tail,
                                                unsigned* __restrict__ bucket) {
  __shared__ int hist[NBUK], wbase[NBUK], loc[NBUK];
  const int tid = threadIdx.x;
  const int beg = blockIdx.x * EPB;
  const int end = min(beg + EPB, NE);
  const int* col = ei + NE;
  for (int b = tid; b < NBUK; b += 256) { hist[b] = 0; loc[b] = 0; }
  __syncthreads();
  for (int e = beg + tid * 4; e < end; e += 1024) {
    int4 c4 = *(const int4*)(col + e);
    atomicAdd(&hist[c4.x >> 8], 1);
    atomicAdd(&hist[c4.y >> 8], 1);
    atomicAdd(&hist[c4.z >> 8], 1);
    atomicAdd(&hist[c4.w >> 8], 1);
  }
  __syncthreads();
  for (int b = tid; b < NBUK; b += 256)
    wbase[b] = atomicAdd(&tail[b], hist[b]);   // contiguous block-private run
  __syncthreads();
  for (int e = beg + tid * 4; e < end; e += 1024) {
    int4 c4 = *(const int4*)(col + e);         // L2-hot re-read
    int4 r4 = *(const int4*)(ei + e);
    {
      int b = c4.x >> 8;
      unsigned pos = (unsigned)(wbase[b] + atomicAdd(&loc[b], 1));
      if (pos < BCAP) bucket[(size_t)b * BCAP + pos] = ((unsigned)r4.x << 8) | (unsigned)(c4.x & 255);
    }
    {
      int b = c4.y >> 8;
      unsigned pos = (unsigned)(wbase[b] + atomicAdd(&loc[b], 1));
      if (pos < BCAP) bucket[(size_t)b * BCAP + pos] = ((unsigned)r4.y << 8) | (unsigned)(c4.y & 255);
    }
    {
      int b = c4.z >> 8;
      unsigned pos = (unsigned)(wbase[b] + atomicAdd(&loc[b], 1));
      if (pos < BCAP) bucket[(size_t)b * BCAP + pos] = ((unsigned)r4.z << 8) | (unsigned)(c4.z & 255);
    }
    {
      int b = c4.w >> 8;
      unsigned pos = (unsigned)(wbase[b] + atomicAdd(&loc[b], 1));
      if (pos < BCAP) bucket[(size_t)b * BCAP + pos] = ((unsigned)r4.w << 8) | (unsigned)(c4.w & 255);
    }
  }
}

// ---------------- bucket-start prefix sum (391 elems, 1 block) ----------------

__global__ void k_bstart(const int* __restrict__ tail, int* __restrict__ bstart) {
  const int tid = threadIdx.x, lane = tid & 63, wid = tid >> 6;   // 512 thr
  int v = (tid < NBUK) ? min(tail[tid], BCAP) : 0;
  int s = v;
  #pragma unroll
  for (int d = 1; d < 64; d <<= 1) { int t = __shfl_up(s, d, 64); if (lane >= d) s += t; }
  __shared__ int wsum[8];
  if (lane == 63) wsum[wid] = s;
  __syncthreads();
  int wpre = 0;
  for (int w = 0; w < wid; ++w) wpre += wsum[w];
  int excl = wpre + s - v;
  if (tid <= NBUK) bstart[tid] = excl;     // bstart[NBUK] = total
}

// ---------------- per-bucket LDS counting sort -> CSR + offsets + dinv ----------------

__global__ __launch_bounds__(256) void k_sort(const unsigned* __restrict__ bucket,
                                              const int* __restrict__ tail,
                                              const int* __restrict__ bstart,
                                              int* __restrict__ csr_src,
                                              int* __restrict__ offsets,
                                              float* __restrict__ dinv) {
  __shared__ int h[256], base_[256], loc[256];
  __shared__ int sorted[BCAP];              // 34.8 KB
  __shared__ int wsum[4];
  const int b = blockIdx.x;
  const int lo = b << 8;
  const int nc = min(256, NN - lo);
  const int n = min(tail[b], BCAP);
  const int seg0 = bstart[b];
  const unsigned* __restrict__ bk = bucket + (size_t)b * BCAP;
  const int tid = threadIdx.x, lane = tid & 63, wid = tid >> 6;
  h[tid] = 0; loc[tid] = 0;
  __syncthreads();
  int i = tid * 4;
  for (; i + 3 < n; i += 1024) {
    uint4 v = *(const uint4*)(bk + i);
    atomicAdd(&h[v.x & 255u], 1);
    atomicAdd(&h[v.y & 255u], 1);
    atomicAdd(&h[v.z & 255u], 1);
    atomicAdd(&h[v.w & 255u], 1);
  }
  for (; i < n; ++i) atomicAdd(&h[bk[i] & 255u], 1);
  __syncthreads();
  {  // exclusive scan of h[0..255]
    int v = h[tid];
    int s = v;
    #pragma unroll
    for (int d = 1; d < 64; d <<= 1) { int t = __shfl_up(s, d, 64); if (lane >= d) s += t; }
    if (lane == 63) wsum[wid] = s;
    __syncthreads();
    int wpre = 0;
    #pragma unroll
    for (int w = 0; w < 4; ++w) if (w < wid) wpre += wsum[w];
    int excl = wpre + s - v;
    base_[tid] = excl;
    if (tid < nc) {
      dinv[lo + tid] = rsqrtf((float)(v + 1));       // +1 = self-loop
      offsets[lo + tid] = seg0 + excl;
    }
  }
  if (b == 0 && tid == 0) offsets[NN] = bstart[NBUK];
  __syncthreads();
  i = tid * 4;
  for (; i + 3 < n; i += 1024) {
    uint4 v = *(const uint4*)(bk + i);
    { int c = v.x & 255u; sorted[base_[c] + atomicAdd(&loc[c], 1)] = (int)(v.x >> 8); }
    { int c = v.y & 255u; sorted[base_[c] + atomicAdd(&loc[c], 1)] = (int)(v.y >> 8); }
    { int c = v.z & 255u; sorted[base_[c] + atomicAdd(&loc[c], 1)] = (int)(v.z >> 8); }
    { int c = v.w & 255u; sorted[base_[c] + atomicAdd(&loc[c], 1)] = (int)(v.w >> 8); }
  }
  for (; i < n; ++i) {
    unsigned ent = bk[i];
    int c = ent & 255u;
    sorted[base_[c] + atomicAdd(&loc[c], 1)] = (int)(ent >> 8);
  }
  __syncthreads();
  for (int t = tid; t < n; t += 256) csr_src[seg0 + t] = sorted[t];   // coalesced
}

// ---------------- layer 1 GEMM: m1b = bf16(dinv * (x @ W1)), 128 -> 64 --------

__global__ __launch_bounds__(256) void k_gemm1(const float* __restrict__ x,
                                               const float* __restrict__ W1,
                                               const float* __restrict__ dinv,
                                               unsigned* __restrict__ m1b) {
  __shared__ float ws[128 * 64];   // 32 KB
  __shared__ float xs[16 * 128];   //  8 KB
  const int tid = threadIdx.x;
  for (int k = tid; k < 128 * 64; k += 256) ws[k] = W1[k];
  const int row0 = blockIdx.x * 16;                    // 6250 blocks
  for (int k = tid; k < 16 * 128; k += 256) xs[k] = x[row0 * 128 + k];
  __syncthreads();
  const int c = tid & 63;
  const int rg = tid >> 6;
  float acc0 = 0.f, acc1 = 0.f, acc2 = 0.f, acc3 = 0.f;
  const float4* xs4 = (const float4*)xs;
  #pragma unroll 8
  for (int k4 = 0; k4 < 32; ++k4) {
    float4 xv0 = xs4[(rg * 4 + 0) * 32 + k4];
    float4 xv1 = xs4[(rg * 4 + 1) * 32 + k4];
    float4 xv2 = xs4[(rg * 4 + 2) * 32 + k4];
    float4 xv3 = xs4[(rg * 4 + 3) * 32 + k4];
    float w0 = ws[(k4 * 4 + 0) * 64 + c];
    float w1 = ws[(k4 * 4 + 1) * 64 + c];
    float w2 = ws[(k4 * 4 + 2) * 64 + c];
    float w3 = ws[(k4 * 4 + 3) * 64 + c];
    acc0 = fmaf(xv0.x, w0, fmaf(xv0.y, w1, fmaf(xv0.z, w2, fmaf(xv0.w, w3, acc0))));
    acc1 = fmaf(xv1.x, w0, fmaf(xv1.y, w1, fmaf(xv1.z, w2, fmaf(xv1.w, w3, acc1))));
    acc2 = fmaf(xv2.x, w0, fmaf(xv2.y, w1, fmaf(xv2.z, w2, fmaf(xv2.w, w3, acc2))));
    acc3 = fmaf(xv3.x, w0, fmaf(xv3.y, w1, fmaf(xv3.z, w2, fmaf(xv3.w, w3, acc3))));
  }
  const int r0 = row0 + rg * 4;
  acc0 *= dinv[r0 + 0];
  acc1 *= dinv[r0 + 1];
  acc2 *= dinv[r0 + 2];
  acc3 *= dinv[r0 + 3];
  // pair channel c (even) with c+1 via lane shuffle, pack bf16x2
  float n0 = __shfl_xor(acc0, 1, 64);
  float n1 = __shfl_xor(acc1, 1, 64);
  float n2 = __shfl_xor(acc2, 1, 64);
  float n3 = __shfl_xor(acc3, 1, 64);
  if (!(c & 1)) {
    const int cb = c >> 1;
    m1b[(r0 + 0) * 32 + cb] = pack2(acc0, n0);
    m1b[(r0 + 1) * 32 + cb] = pack2(acc1, n1);
    m1b[(r0 + 2) * 32 + cb] = pack2(acc2, n2);
    m1b[(r0 + 3) * 32 + cb] = pack2(acc3, n3);
  }
}

// ---------------- unpack-accumulate: uint4 = 8 bf16 channels ----------------

#define ACC8(v, f)                                                   \
  acc[0] = fmaf(__uint_as_float((v).x << 16), (f), acc[0]);          \
  acc[1] = fmaf(__uint_as_float((v).x & 0xffff0000u), (f), acc[1]);  \
  acc[2] = fmaf(__uint_as_float((v).y << 16), (f), acc[2]);          \
  acc[3] = fmaf(__uint_as_float((v).y & 0xffff0000u), (f), acc[3]);  \
  acc[4] = fmaf(__uint_as_float((v).z << 16), (f), acc[4]);          \
  acc[5] = fmaf(__uint_as_float((v).z & 0xffff0000u), (f), acc[5]);  \
  acc[6] = fmaf(__uint_as_float((v).w << 16), (f), acc[6]);          \
  acc[7] = fmaf(__uint_as_float((v).w & 0xffff0000u), (f), acc[7]);

// ---------------- layer 1 aggregation (bf16 rows, 8 rows/instr) -------------
// Lane layout: e = lane>>3 (edge slot 0..7), q = lane&7 (16B chunk = 8 ch).
// Chunk = 32 edges via 4 dwordx4 gathers (8 rows each). Invalid slots clamp
// index to beg and contribute via fma x0.0. fp32 accumulate.

__global__ __launch_bounds__(256) void k_agg1(const unsigned* __restrict__ m1b,
                                              const int* __restrict__ offsets,
                                              const int* __restrict__ csr_src,
                                              const float* __restrict__ dinv,
                                              const float* __restrict__ b1,
                                              float* __restrict__ a1) {
  const int node = blockIdx.x * 4 + (threadIdx.x >> 6);
  const int lane = threadIdx.x & 63;
  const int e = lane >> 3;
  const int q = lane & 7;
  const uint4* __restrict__ m1v = (const uint4*)m1b;
  const int beg = offsets[node], end = offsets[node + 1];
  float acc[8];
  #pragma unroll
  for (int j = 0; j < 8; ++j) acc[j] = 0.f;
  for (int p = beg; p < end; p += 32) {
    const int i0 = p + e, i1 = p + 8 + e, i2 = p + 16 + e, i3 = p + 24 + e;
    const int s0 = csr_src[i0 < end ? i0 : beg];
    const int s1 = csr_src[i1 < end ? i1 : beg];
    const int s2 = csr_src[i2 < end ? i2 : beg];
    const int s3 = csr_src[i3 < end ? i3 : beg];
    const float f0 = (i0 < end) ? 1.f : 0.f;
    const float f1 = (i1 < end) ? 1.f : 0.f;
    const float f2 = (i2 < end) ? 1.f : 0.f;
    const float f3 = (i3 < end) ? 1.f : 0.f;
    uint4 v0 = m1v[s0 * 8 + q];
    uint4 v1 = m1v[s1 * 8 + q];
    uint4 v2 = m1v[s2 * 8 + q];
    uint4 v3 = m1v[s3 * 8 + q];
    ACC8(v0, f0);
    ACC8(v1, f1);
    ACC8(v2, f2);
    ACC8(v3, f3);
  }
  // reduce the 8 edge slots; channel chunk q stays put
  #pragma unroll
  for (int j = 0; j < 8; ++j) {
    acc[j] += __shfl_xor(acc[j], 8, 64);
    acc[j] += __shfl_xor(acc[j], 16, 64);
    acc[j] += __shfl_xor(acc[j], 32, 64);
  }
  if (e == 0) {                       // lanes 0..7 hold chunk q = lane
    uint4 sv = m1v[node * 8 + q];     // self-loop row
    const float d = dinv[node];
    float4 bb0 = ((const float4*)b1)[q * 2];
    float4 bb1 = ((const float4*)b1)[q * 2 + 1];
    float4 o0, o1;
    o0.x = (acc[0] + __uint_as_float(sv.x << 16)) * d + bb0.x;
    o0.y = (acc[1] + __uint_as_float(sv.x & 0xffff0000u)) * d + bb0.y;
    o0.z = (acc[2] + __uint_as_float(sv.y << 16)) * d + bb0.z;
    o0.w = (acc[3] + __uint_as_float(sv.y & 0xffff0000u)) * d + bb0.w;
    o1.x = (acc[4] + __uint_as_float(sv.z << 16)) * d + bb1.x;
    o1.y = (acc[5] + __uint_as_float(sv.z & 0xffff0000u)) * d + bb1.y;
    o1.z = (acc[6] + __uint_as_float(sv.w << 16)) * d + bb1.z;
    o1.w = (acc[7] + __uint_as_float(sv.w & 0xffff0000u)) * d + bb1.w;
    ((float4*)a1)[node * 16 + q * 2] = o0;
    ((float4*)a1)[node * 16 + q * 2 + 1] = o1;
  }
}

// ---------------- layer 2 GEMM: m2b = bf16(dinv * (a1 @ W2)), 64 -> 40 ------

__global__ __launch_bounds__(256) void k_gemm2(const float* __restrict__ a1,
                                               const float* __restrict__ W2,
                                               const float* __restrict__ dinv,
                                               unsigned* __restrict__ m2b) {
  __shared__ float ws[64 * 40];    // 10 KB
  const int tid = threadIdx.x;
  for (int k = tid; k < 64 * 40; k += 256) ws[k] = W2[k];
  __syncthreads();
  const int idx = blockIdx.x * 256 + tid;                // thread = (node, ch-pair)
  if (idx >= NN * 20) return;
  const int node = idx / 20;
  const int c0 = (idx - node * 20) * 2;
  const float4* __restrict__ a4 = (const float4*)(a1 + node * 64);
  float acc0 = 0.f, acc1 = 0.f;
  #pragma unroll
  for (int k4 = 0; k4 < 16; ++k4) {
    float4 a = a4[k4];
    acc0 = fmaf(a.x, ws[(k4 * 4 + 0) * 40 + c0], acc0);
    acc1 = fmaf(a.x, ws[(k4 * 4 + 0) * 40 + c0 + 1], acc1);
    acc0 = fmaf(a.y, ws[(k4 * 4 + 1) * 40 + c0], acc0);
    acc1 = fmaf(a.y, ws[(k4 * 4 + 1) * 40 + c0 + 1], acc1);
    acc0 = fmaf(a.z, ws[(k4 * 4 + 2) * 40 + c0], acc0);
    acc1 = fmaf(a.z, ws[(k4 * 4 + 2) * 40 + c0 + 1], acc1);
    acc0 = fmaf(a.w, ws[(k4 * 4 + 3) * 40 + c0], acc0);
    acc1 = fmaf(a.w, ws[(k4 * 4 + 3) * 40 + c0 + 1], acc1);
  }
  const float d = dinv[node];
  m2b[idx] = pack2(acc0 * d, acc1 * d);
}

// ---------------- layer 2 aggregation + bias + log_softmax ------------------
// Lane layout: e = lane/5 (edge slot 0..11), q = lane%5 (16B chunk = 8 ch);
// lanes 60..63 masked (f=0). Chunk = 48 edges via 4 dwordx4 gathers (12
// rows each). Reduce 12 slots via shfl (+30, +15, +5/+10); log_softmax
// over 5 lanes x 8 comps via width-8 xor (lanes 5..7 seeded -inf/0).

__device__ __forceinline__ float shfl1(float v, int src) {
  return __shfl(v, src & 63, 64);
}

__global__ __launch_bounds__(256) void k_agg2(const unsigned* __restrict__ m2b,
                                              const int* __restrict__ offsets,
                                              const int* __restrict__ csr_src,
                                              const float* __restrict__ dinv,
                                              const float* __restrict__ b2,
                                              float* __restrict__ out) {
  const int node = blockIdx.x * 4 + (threadIdx.x >> 6);
  const int lane = threadIdx.x & 63;
  const bool act = lane < 60;
  const int e = act ? (lane / 5) : 0;
  const int q = act ? (lane - e * 5) : 0;
  const uint4* __restrict__ m2v = (const uint4*)m2b;
  const int beg = offsets[node], end = offsets[node + 1];
  float acc[8];
  #pragma unroll
  for (int j = 0; j < 8; ++j) acc[j] = 0.f;
  for (int p = beg; p < end; p += 48) {
    const int i0 = p + e, i1 = p + 12 + e, i2 = p + 24 + e, i3 = p + 36 + e;
    const int s0 = csr_src[i0 < end ? i0 : beg];
    const int s1 = csr_src[i1 < end ? i1 : beg];
    const int s2 = csr_src[i2 < end ? i2 : beg];
    const int s3 = csr_src[i3 < end ? i3 : beg];
    const float f0 = (act && i0 < end) ? 1.f : 0.f;
    const float f1 = (act && i1 < end) ? 1.f : 0.f;
    const float f2 = (act && i2 < end) ? 1.f : 0.f;
    const float f3 = (act && i3 < end) ? 1.f : 0.f;
    uint4 v0 = m2v[s0 * 5 + q];
    uint4 v1 = m2v[s1 * 5 + q];
    uint4 v2 = m2v[s2 * 5 + q];
    uint4 v3 = m2v[s3 * 5 + q];
    ACC8(v0, f0);
    ACC8(v1, f1);
    ACC8(v2, f2);
    ACC8(v3, f3);
  }
  // reduce 12 slots: lanes 0..29 += lanes+30; lanes 0..14 += lanes+15;
  // lanes 0..4 += lanes+5 and lanes+10
  #pragma unroll
  for (int j = 0; j < 8; ++j) acc[j] += shfl1(acc[j], lane + 30);
  #pragma unroll
  for (int j = 0; j < 8; ++j) acc[j] += shfl1(acc[j], lane + 15);
  #pragma unroll
  for (int j = 0; j < 8; ++j) {
    float t1 = shfl1(acc[j], lane + 5);
    float t2 = shfl1(acc[j], lane + 10);
    acc[j] += t1 + t2;
  }
  const bool lead = (lane < 5);
  float r[8];
  #pragma unroll
  for (int j = 0; j < 8; ++j) r[j] = 0.f;
  if (lead) {
    uint4 sv = m2v[node * 5 + lane];   // self-loop row (q == lane here)
    const float d = dinv[node];
    float4 bb0 = ((const float4*)b2)[lane * 2];
    float4 bb1 = ((const float4*)b2)[lane * 2 + 1];
    r[0] = (acc[0] + __uint_as_float(sv.x << 16)) * d + bb0.x;
    r[1] = (acc[1] + __uint_as_float(sv.x & 0xffff0000u)) * d + bb0.y;
    r[2] = (acc[2] + __uint_as_float(sv.y << 16)) * d + bb0.z;
    r[3] = (acc[3] + __uint_as_float(sv.y & 0xffff0000u)) * d + bb0.w;
    r[4] = (acc[4] + __uint_as_float(sv.z << 16)) * d + bb1.x;
    r[5] = (acc[5] + __uint_as_float(sv.z & 0xffff0000u)) * d + bb1.y;
    r[6] = (acc[6] + __uint_as_float(sv.w << 16)) * d + bb1.z;
    r[7] = (acc[7] + __uint_as_float(sv.w & 0xffff0000u)) * d + bb1.w;
  }
  // log_softmax over 40 = 5 lanes x 8 comps (width-8 xor; lanes 5..7 seeded)
  float mx = -INFINITY;
  if (lead) {
    mx = fmaxf(fmaxf(fmaxf(r[0], r[1]), fmaxf(r[2], r[3])),
               fmaxf(fmaxf(r[4], r[5]), fmaxf(r[6], r[7])));
  }
  #pragma unroll
  for (int d = 4; d > 0; d >>= 1) mx = fmaxf(mx, __shfl_xor(mx, d, 8));
  float se = 0.f;
  if (lead) {
    se = __expf(r[0] - mx) + __expf(r[1] - mx) + __expf(r[2] - mx) +
         __expf(r[3] - mx) + __expf(r[4] - mx) + __expf(r[5] - mx) +
         __expf(r[6] - mx) + __expf(r[7] - mx);
  }
  #pragma unroll
  for (int d = 4; d > 0; d >>= 1) se += __shfl_xor(se, d, 8);
  if (lead) {
    const float lse = mx + logf(se);
    float4 o0, o1;
    o0.x = r[0] - lse; o0.y = r[1] - lse; o0.z = r[2] - lse; o0.w = r[3] - lse;
    o1.x = r[4] - lse; o1.y = r[5] - lse; o1.z = r[6] - lse; o1.w = r[7] - lse;
    ((float4*)out)[node * 10 + lane * 2] = o0;
    ((float4*)out)[node * 10 + lane * 2 + 1] = o1;
  }
}

// ---------------- launch ----------------

extern "C" void kernel_launch(void* const* d_in, const int* in_sizes, int n_in,
                              void* d_out, int out_size, void* d_ws, size_t ws_size,
                              hipStream_t stream) {
  const float* x   = (const float*)d_in[0];
  const int*   ei  = (const int*)d_in[1];   // [2][NE], int32
  const float* W1  = (const float*)d_in[3];
  const float* b1  = (const float*)d_in[4];
  const float* W2  = (const float*)d_in[5];
  const float* b2  = (const float*)d_in[6];
  float*       out = (float*)d_out;

  char* ws = (char*)d_ws;
  int*      tail    = (int*)(ws + 0);                            // NBUK ints
  int*      bstart  = (int*)(ws + (size_t)4 * 1024);             // NBUK+1 ints
  int*      offsets = (int*)(ws + (size_t)8 * 1024);             // (NN+1)*4 = 400KB
  float*    dinv    = (float*)(ws + (size_t)512 * 1024);         // NN*4 = 400KB
  int*      csr_src = (int*)(ws + (size_t)1024 * 1024);          // NE*4 = 12.8MB
  unsigned* bucket  = (unsigned*)(ws + (size_t)14 * 1024 * 1024);// 13.6MB, dead after k_sort
  unsigned* m1b     = (unsigned*)(ws + (size_t)14 * 1024 * 1024);// 12.8MB bf16 (overlays bucket)
  float*    a1      = (float*)(ws + (size_t)40 * 1024 * 1024);   // 25.6MB fp32
  unsigned* m2b     = m1b;  // m1b dead after agg1 (NN*20*4 = 8MB)

  k_zero<<<2, 256, 0, stream>>>(tail, NBUK);
  k_bucket<<<(NE + EPB - 1) / EPB, 256, 0, stream>>>(ei, tail, bucket);
  k_bstart<<<1, 512, 0, stream>>>(tail, bstart);
  k_sort<<<NBUK, 256, 0, stream>>>(bucket, tail, bstart, csr_src, offsets, dinv);
  k_gemm1<<<NN / 16, 256, 0, stream>>>(x, W1, dinv, m1b);
  k_agg1<<<NN / 4, 256, 0, stream>>>(m1b, offsets, csr_src, dinv, b1, a1);
  k_gemm2<<<(NN * 20 + 255) / 256, 256, 0, stream>>>(a1, W2, dinv, m2b);
  k_agg2<<<NN / 4, 256, 0, stream>>>(m2b, offsets, csr_src, dinv, b2, out);
}